// Round 6
// baseline (290.066 us; speedup 1.0000x reference)
//
#include <hip/hip_runtime.h>
#include <hip/hip_bf16.h>
#include <math.h>

// Problem constants: x[B=16][T=4096][D=512], W[512][512], v[512]
#define BB 16
#define TT 4096
#define DD 512
#define MM (BB*TT)   // 65536 rows

typedef __bf16 bf16x8 __attribute__((ext_vector_type(8)));
typedef float  f32x4  __attribute__((ext_vector_type(4)));

__device__ inline unsigned short f2bf(float f) {
    unsigned u = __builtin_bit_cast(unsigned, f) + 0x8000u;  // round-half-away
    return (unsigned short)(u >> 16);
}

// pack two fp32 -> two bf16 in one u32 (2 v_add + 1 v_perm)
__device__ inline unsigned pack_bf16x2(float lo, float hi) {
    unsigned u0 = __builtin_bit_cast(unsigned, lo) + 0x8000u;
    unsigned u1 = __builtin_bit_cast(unsigned, hi) + 0x8000u;
    return __builtin_amdgcn_perm(u1, u0, 0x07060302);  // [u1.hi16, u0.hi16]
}

// fast tanh: 1 - 2/(e^{2y}+1).  |y| <~ 1.5 here, no overflow concerns.
__device__ inline float tanh_fast(float y) {
    float e = __expf(2.0f * y);
    return 1.0f - 2.0f * __builtin_amdgcn_rcpf(e + 1.0f);
}

// ---------------- W fp32 -> Wb bf16, WAVE-STREAM fragment order ----------------
// Layout index: (((wid*4 + p)*16 + s)*2 + ni)*64 + lane, 8 elems each.
// Fragment (wid,p,s,ni): lane holds B[k = s*32+(lane>>4)*8+j][n = ((p*4+wid)*2+ni)*16 + (lane&15)].
// => in scores_kernel, wave wid's B reads are a single monotone 2 KB/step stream
//    (one rolling pointer; no big constant-offset fan; no address-reg spills - R3-R5 lesson).
__global__ void wb_kernel(const float* __restrict__ W, unsigned short* __restrict__ Wb) {
    int u = blockIdx.x * 256 + threadIdx.x;   // 0..32767
    int lane = u & 63;
    int ni   = (u >> 6) & 1;
    int s    = (u >> 7) & 15;
    int p    = (u >> 11) & 3;
    int wid  = u >> 13;
    int n  = ((p * 4 + wid) * 2 + ni) * 16 + (lane & 15);
    int k0 = s * 32 + (lane >> 4) * 8;
    unsigned short o[8];
    #pragma unroll
    for (int j = 0; j < 8; j++) o[j] = f2bf(W[(size_t)(k0 + j) * DD + n]);
    *(uint4*)(Wb + (size_t)u * 8) = *(uint4*)o;   // coalesced 16 B store
}

// ---------------- Fused GEMM + tanh + v-dot -> final scores ----------------
// Block = 64 rows x full N=512 x full K=512.  4 waves; pass p: wave w owns cols
// [(p*4+w)*32, +32) as a 4x2 frag tile (16x16x32 MFMA, full-K accumulate).
// A-strip (64x512 bf16 = 64 KB) staged ONCE into LDS (fp32->bf16, XOR chunk swizzle).
// B streamed from wave-ordered Wb via ONE rolling pointer, ring-4 (3-step lookahead),
// cross-pass prefetch unified via global step g = p*16+s.  ZERO barriers in K-loop.
__global__ __launch_bounds__(256, 2) void scores_kernel(
        const float* __restrict__ x, const unsigned short* __restrict__ Wb,
        const float* __restrict__ v, float* __restrict__ scores) {
    __shared__ unsigned short As[64 * DD];   // 64 KB
    __shared__ float sbuf[4][64];

    const int tid  = threadIdx.x;
    const int m0   = blockIdx.x * 64;
    const int wid  = tid >> 6;
    const int lane = tid & 63;
    const int l15  = lane & 15;
    const int q    = lane >> 4;
    const int r3   = l15 & 7;

    // rolling B stream pointer: wave base + lane slot
    const unsigned short* bqp = Wb + ((size_t)wid << 16) + lane * 8;

    // Prime ring slots 0..2 (g = 0,1,2) BEFORE staging: L2 latency hides under A stage.
    bf16x8 b[4][2];
    #pragma unroll
    for (int g = 0; g < 3; g++) {
        b[g][0] = *(const bf16x8*)(bqp);
        b[g][1] = *(const bf16x8*)(bqp + 512);
        bqp += 1024;
    }

    // ---- Stage A: 64 rows x 512 cols fp32 -> bf16, XOR-swizzled.
    // Wave-iter = one full row (64 lanes x 32 B = 2 KB contiguous global read).
    #pragma unroll 4
    for (int i = 0; i < 16; i++) {
        int u = i * 256 + tid;           // 0..4095 (16-B output chunk id)
        int r = u >> 6;                  // 64 chunks per row
        int c = u & 63;
        const float* gp = x + (size_t)(m0 + r) * DD + c * 8;
        float4 f0 = *(const float4*)(gp);
        float4 f1 = *(const float4*)(gp + 4);
        uint4 o;
        o.x = pack_bf16x2(f0.x, f0.y);
        o.y = pack_bf16x2(f0.z, f0.w);
        o.z = pack_bf16x2(f1.x, f1.y);
        o.w = pack_bf16x2(f1.z, f1.w);
        *(uint4*)(&As[r * DD + (c ^ (r & 7)) * 8]) = o;
    }
    __syncthreads();   // the only barrier before the epilogue

    float vpart[4][4];
    #pragma unroll
    for (int mi = 0; mi < 4; mi++)
        #pragma unroll
        for (int rr = 0; rr < 4; rr++)
            vpart[mi][rr] = 0.f;

    // A-frag: row R = mi*16+l15, logical chunk c = s*4+q, stored at c^(R&7)
#define A_FRAG(mi, s) (*(const bf16x8*)(&As[((mi)*16 + l15) * DD + ((((s)*4 + q) ^ r3) * 8)]))

    bf16x8 a[2][4];
    #pragma unroll
    for (int mi = 0; mi < 4; mi++) a[0][mi] = A_FRAG(mi, 0);

    #pragma unroll
    for (int p = 0; p < 4; p++) {
        f32x4 acc[4][2];
        #pragma unroll
        for (int mi = 0; mi < 4; mi++)
            #pragma unroll
            for (int ni = 0; ni < 2; ni++)
                acc[mi][ni] = (f32x4){0.f, 0.f, 0.f, 0.f};

        #pragma unroll
        for (int s = 0; s < 16; s++) {
            const int g   = p * 16 + s;
            const int cur = g & 1;
            if (g < 63) {     // next A frag (s wraps: pass p+1 reuses same A data)
                const int ns = (s + 1) & 15;
                #pragma unroll
                for (int mi = 0; mi < 4; mi++) a[cur ^ 1][mi] = A_FRAG(mi, ns);
            }
            if (g < 61) {     // B stream, 3-step lookahead
                b[(g + 3) & 3][0] = *(const bf16x8*)(bqp);
                b[(g + 3) & 3][1] = *(const bf16x8*)(bqp + 512);
                bqp += 1024;
            }
            #pragma unroll
            for (int mi = 0; mi < 4; mi++)
                #pragma unroll
                for (int ni = 0; ni < 2; ni++)
                    acc[mi][ni] = __builtin_amdgcn_mfma_f32_16x16x32_bf16(
                        a[cur][mi], b[g & 3][ni], acc[mi][ni], 0, 0, 0);
        }

        // epilogue: tanh + v-dot into per-row partials
        // C/D layout (16x16): col = lane&15, row = q*4 + rr  [m89/m91 verified]
        float vv[2];
        vv[0] = v[(p * 4 + wid) * 32 + l15];
        vv[1] = v[(p * 4 + wid) * 32 + 16 + l15];
        #pragma unroll
        for (int mi = 0; mi < 4; mi++)
            #pragma unroll
            for (int ni = 0; ni < 2; ni++)
                #pragma unroll
                for (int rr = 0; rr < 4; rr++)
                    vpart[mi][rr] += tanh_fast(acc[mi][ni][rr]) * vv[ni];
    }
#undef A_FRAG

    // cross-lane reduce over the 16 col-lanes, then cross-wave via LDS
    #pragma unroll
    for (int mi = 0; mi < 4; mi++)
        #pragma unroll
        for (int rr = 0; rr < 4; rr++) {
            float sum = vpart[mi][rr];
            sum += __shfl_xor(sum, 1);
            sum += __shfl_xor(sum, 2);
            sum += __shfl_xor(sum, 4);
            sum += __shfl_xor(sum, 8);
            if (l15 == 0)
                sbuf[wid][mi * 16 + q * 4 + rr] = sum;
        }
    __syncthreads();
    if (tid < 64)
        scores[m0 + tid] = sbuf[0][tid] + sbuf[1][tid] + sbuf[2][tid] + sbuf[3][tid];
}

// ---------------- Softmax over T per batch ----------------
__global__ void softmax_kernel(const float* __restrict__ scores, float* __restrict__ weights) {
    const int b = blockIdx.x;
    const int tid = threadIdx.x;     // 256 threads, 16 elems each
    __shared__ float wred[4];

    float s[16];
    float mx = -1e30f;
    #pragma unroll
    for (int i = 0; i < 16; i++) {
        float sv = scores[b * TT + i * 256 + tid];
        s[i] = sv;
        mx = fmaxf(mx, sv);
    }
    #pragma unroll
    for (int off = 32; off; off >>= 1) mx = fmaxf(mx, __shfl_xor(mx, off));
    if ((tid & 63) == 0) wred[tid >> 6] = mx;
    __syncthreads();
    mx = fmaxf(fmaxf(wred[0], wred[1]), fmaxf(wred[2], wred[3]));
    __syncthreads();

    float sum = 0.f;
    #pragma unroll
    for (int i = 0; i < 16; i++) { s[i] = __expf(s[i] - mx); sum += s[i]; }
    #pragma unroll
    for (int off = 32; off; off >>= 1) sum += __shfl_xor(sum, off);
    if ((tid & 63) == 0) wred[tid >> 6] = sum;
    __syncthreads();
    sum = wred[0] + wred[1] + wred[2] + wred[3];

    const float inv = 1.0f / sum;
    #pragma unroll
    for (int i = 0; i < 16; i++)
        weights[b * TT + i * 256 + tid] = s[i] * inv;
}

// ---------------- Pooling: out[b,d] = sum_t w[b,t] * x[b,t,d] ----------------
// 1024 blocks (4/CU) x 256 thr; lane = float4 column, two t-phases combined in LDS
// before 4 atomics/thread.
#define PTCH 64
__global__ __launch_bounds__(256) void pool_kernel(
        const float* __restrict__ x, const float* __restrict__ weights,
        float* __restrict__ out) {
    __shared__ float wsm[PTCH];
    __shared__ f32x4 psum[128];
    const int b   = blockIdx.y;
    const int t0  = blockIdx.x * PTCH;
    const int tid = threadIdx.x;
    if (tid < PTCH) wsm[tid] = weights[b * TT + t0 + tid];
    __syncthreads();

    const int dq = tid & 127;    // float4 column 0..127
    const int ts = tid >> 7;     // t parity
    f32x4 acc = (f32x4){0.f, 0.f, 0.f, 0.f};
    const float* xp = x + ((size_t)b * TT + t0 + ts) * DD + dq * 4;
    #pragma unroll 8
    for (int t = ts; t < PTCH; t += 2) {
        f32x4 xv = *(const f32x4*)xp;
        acc += wsm[t] * xv;
        xp += 2 * DD;
    }
    if (ts == 1) psum[dq] = acc;
    __syncthreads();
    if (ts == 0) {
        acc += psum[dq];
        float* op = out + b * DD + dq * 4;
        atomicAdd(op + 0, acc[0]);
        atomicAdd(op + 1, acc[1]);
        atomicAdd(op + 2, acc[2]);
        atomicAdd(op + 3, acc[3]);
    }
}

extern "C" void kernel_launch(void* const* d_in, const int* in_sizes, int n_in,
                              void* d_out, int out_size, void* d_ws, size_t ws_size,
                              hipStream_t stream) {
    (void)in_sizes; (void)n_in; (void)out_size; (void)ws_size;
    const float* x = (const float*)d_in[0];
    const float* W = (const float*)d_in[1];
    const float* v = (const float*)d_in[2];
    float* out = (float*)d_out;

    // ws layout: Wb bf16 wave-stream order (512 KB) | scores fp32 (256 KB) | weights fp32 (256 KB)
    unsigned short* Wb = (unsigned short*)d_ws;
    float* scores      = (float*)((char*)d_ws + 512 * 1024);
    float* weights     = (float*)((char*)d_ws + 512 * 1024 + 256 * 1024);

    hipMemsetAsync(d_out, 0, BB * DD * sizeof(float), stream);

    wb_kernel<<<128, 256, 0, stream>>>(W, Wb);

    scores_kernel<<<MM / 64, 256, 0, stream>>>(x, Wb, v, scores);

    softmax_kernel<<<BB, 256, 0, stream>>>(scores, weights);

    pool_kernel<<<dim3(TT / PTCH, BB), 256, 0, stream>>>(x, weights, out);
}

// Round 7
// 254.684 us; speedup vs baseline: 1.1389x; 1.1389x over previous
//
#include <hip/hip_runtime.h>
#include <hip/hip_bf16.h>
#include <math.h>

// Problem constants: x[B=16][T=4096][D=512], W[512][512], v[512]
#define BB 16
#define TT 4096
#define DD 512
#define MM (BB*TT)   // 65536 rows

typedef __bf16 bf16x8 __attribute__((ext_vector_type(8)));
typedef float  f32x4  __attribute__((ext_vector_type(4)));

__device__ inline unsigned short f2bf(float f) {
    unsigned u = __builtin_bit_cast(unsigned, f) + 0x8000u;  // round-half-away
    return (unsigned short)(u >> 16);
}

// pack two fp32 -> two bf16 in one u32 (2 v_add + 1 v_perm)
__device__ inline unsigned pack_bf16x2(float lo, float hi) {
    unsigned u0 = __builtin_bit_cast(unsigned, lo) + 0x8000u;
    unsigned u1 = __builtin_bit_cast(unsigned, hi) + 0x8000u;
    return __builtin_amdgcn_perm(u1, u0, 0x07060302);  // [u1.hi16, u0.hi16]
}

// fast tanh: 1 - 2/(e^{2y}+1).  |y| <~ 2 here, no overflow concerns.
__device__ inline float tanh_fast(float y) {
    float e = __expf(2.0f * y);
    return 1.0f - 2.0f * __builtin_amdgcn_rcpf(e + 1.0f);
}

// ---------------- W fp32 -> Wb bf16, wave-stream fragment order ----------------
// frag id fid = ((h*8 + p)*16 + s)*2 + ni   (h = col-half of the wave pair)
// lane of frag holds B[k = s*32 + (lane>>4)*8 + j][n = h*256 + p*32 + ni*16 + (lane&15)]
// => per col-half the K-loop B reads are ONE monotone 2 KB/step stream.
__global__ void wb_kernel(const float* __restrict__ W, unsigned short* __restrict__ Wb) {
    int u = blockIdx.x * 256 + threadIdx.x;   // 0..32767
    int lane = u & 63;
    int fid  = u >> 6;                        // 0..511
    int ni = fid & 1;
    int s  = (fid >> 1) & 15;
    int p  = (fid >> 5) & 7;
    int h  = fid >> 8;
    int n  = h * 256 + p * 32 + ni * 16 + (lane & 15);
    int k0 = s * 32 + (lane >> 4) * 8;
    unsigned short o[8];
    #pragma unroll
    for (int j = 0; j < 8; j++) o[j] = f2bf(W[(size_t)(k0 + j) * DD + n]);
    *(uint4*)(Wb + (size_t)u * 8) = *(uint4*)o;   // coalesced 16 B store
}

// ---------------- Fused GEMM + tanh + v-dot + online-softmax partial pool ----------------
// Block = 64 rows (one batch's chunk) x full N=512 x full K=512.  4 waves:
// wave w: rows (w&1)*32..+32, col-half h=w>>1; 8 passes of a 32x32 acc tile
// (2x2 16x16x32 MFMA frags, full-K accumulate).  A-strip (64x512 bf16 = 64 KB)
// staged ONCE in LDS (fp32->bf16, XOR chunk swizzle).  B streamed via ONE rolling
// pointer, ring-4 (3-step lookahead; stream padded so no guards).  ZERO barriers
// in the K-loop.  Epilogue: block-local softmax (m,Z) + weighted x-sum from LDS
// -> num[512] partial.  x is read from HBM exactly ONCE in the whole pipeline.
// Working set (R4-R6 spill lesson): a 16 + b 32 + acc 16 + vpart 8 + addr ~20 < 128.
__global__ __launch_bounds__(256, 2) void scorepool_kernel(
        const float* __restrict__ x, const unsigned short* __restrict__ Wb,
        const float* __restrict__ v,
        float* __restrict__ num_ws, float* __restrict__ mz_ws) {
    __shared__ unsigned short As[64 * DD];   // 64 KB
    __shared__ float sbuf[2][64];
    __shared__ float ew[64];
    __shared__ float mzsh[2];
    __shared__ float psum[4][DD];            // 8 KB

    const int tid  = threadIdx.x;
    const int m0   = blockIdx.x * 64;
    const int wid  = tid >> 6;
    const int lane = tid & 63;
    const int l15  = lane & 15;
    const int q    = lane >> 4;
    const int r3   = l15 & 7;
    const int wr   = (wid & 1) * 32;   // wave row base
    const int wh   = wid >> 1;         // wave col half

    // ---- Stage A: 64 rows x 512 cols fp32 -> bf16, XOR-swizzled.
    #pragma unroll 4
    for (int i = 0; i < 16; i++) {
        int u = i * 256 + tid;           // 0..4095 (16-B output chunk id)
        int r = u >> 6;                  // 64 chunks per row
        int c = u & 63;
        const float* gp = x + (size_t)(m0 + r) * DD + c * 8;
        float4 f0 = *(const float4*)(gp);
        float4 f1 = *(const float4*)(gp + 4);
        uint4 o;
        o.x = pack_bf16x2(f0.x, f0.y);
        o.y = pack_bf16x2(f0.z, f0.w);
        o.z = pack_bf16x2(f1.x, f1.y);
        o.w = pack_bf16x2(f1.z, f1.w);
        *(uint4*)(&As[r * DD + (c ^ (r & 7)) * 8]) = o;
    }

    // ---- Prime B ring (after staging so boundary pressure stays low;
    //      L2 latency hides under the barrier drain of the staging loads).
    const unsigned short* bqp = Wb + (size_t)wh * 131072 + lane * 8;
    bf16x8 b[4][2];
    #pragma unroll
    for (int g = 0; g < 3; g++) {
        b[g][0] = *(const bf16x8*)(bqp);
        b[g][1] = *(const bf16x8*)(bqp + 512);
        bqp += 1024;
    }

    __syncthreads();   // the only barrier before the epilogue

    float vpart[2][4];
    #pragma unroll
    for (int mi = 0; mi < 2; mi++)
        #pragma unroll
        for (int rr = 0; rr < 4; rr++)
            vpart[mi][rr] = 0.f;

    // A-frag: row R = wr + mi*16 + l15, logical chunk c = s*4+q, stored at c^(R&7)
#define A_FRAG(mi, s) (*(const bf16x8*)(&As[(wr + (mi)*16 + l15) * DD + ((((s)*4 + q) ^ r3) * 8)]))

    bf16x8 a[2][2];
    a[0][0] = A_FRAG(0, 0);
    a[0][1] = A_FRAG(1, 0);

    #pragma unroll 1
    for (int p = 0; p < 8; p++) {
        f32x4 acc[2][2];
        #pragma unroll
        for (int mi = 0; mi < 2; mi++)
            #pragma unroll
            for (int ni = 0; ni < 2; ni++)
                acc[mi][ni] = (f32x4){0.f, 0.f, 0.f, 0.f};

        #pragma unroll
        for (int s = 0; s < 16; s++) {
            const int cur = s & 1;
            const int ns  = (s + 1) & 15;    // pass p+1 reuses same A data
            a[cur ^ 1][0] = A_FRAG(0, ns);
            a[cur ^ 1][1] = A_FRAG(1, ns);
            // B stream, 3-step lookahead (stream padded: tail overrun harmless)
            b[(s + 3) & 3][0] = *(const bf16x8*)(bqp);
            b[(s + 3) & 3][1] = *(const bf16x8*)(bqp + 512);
            bqp += 1024;
            #pragma unroll
            for (int mi = 0; mi < 2; mi++)
                #pragma unroll
                for (int ni = 0; ni < 2; ni++)
                    acc[mi][ni] = __builtin_amdgcn_mfma_f32_16x16x32_bf16(
                        a[cur][mi], b[s & 3][ni], acc[mi][ni], 0, 0, 0);
        }

        // per-pass epilogue: tanh + v-dot into per-row partials
        // C/D layout (16x16): col = lane&15, row = q*4 + rr  [m89/m91 verified]
        float vv0 = v[wh * 256 + p * 32 + l15];
        float vv1 = v[wh * 256 + p * 32 + 16 + l15];
        #pragma unroll
        for (int mi = 0; mi < 2; mi++)
            #pragma unroll
            for (int rr = 0; rr < 4; rr++)
                vpart[mi][rr] += tanh_fast(acc[mi][0][rr]) * vv0
                               + tanh_fast(acc[mi][1][rr]) * vv1;
    }
#undef A_FRAG

    // cross-lane reduce over the 16 col-lanes -> per-col-half row partials
    #pragma unroll
    for (int mi = 0; mi < 2; mi++)
        #pragma unroll
        for (int rr = 0; rr < 4; rr++) {
            float sum = vpart[mi][rr];
            sum += __shfl_xor(sum, 1);
            sum += __shfl_xor(sum, 2);
            sum += __shfl_xor(sum, 4);
            sum += __shfl_xor(sum, 8);
            if (l15 == 0)
                sbuf[wh][wr + mi * 16 + q * 4 + rr] = sum;
        }
    __syncthreads();

    // wave 0: row scores -> block max m, e_r, Z
    if (tid < 64) {
        float s = sbuf[0][tid] + sbuf[1][tid];
        float m = s;
        #pragma unroll
        for (int off = 32; off; off >>= 1) m = fmaxf(m, __shfl_xor(m, off));
        float e = __expf(s - m);
        float z = e;
        #pragma unroll
        for (int off = 32; off; off >>= 1) z += __shfl_xor(z, off);
        ew[tid] = e;
        if (tid == 0) { mzsh[0] = m; mzsh[1] = z; }
    }
    __syncthreads();

    // weighted x-sum from LDS: thread = (rg = tid>>6 row group, cx = tid&63 chunk)
    // num[d] partial = sum_r e_r * xb[r][d]
    const int cx = tid & 63;
    const int rg = tid >> 6;
    float nacc[8];
    #pragma unroll
    for (int j = 0; j < 8; j++) nacc[j] = 0.f;
    #pragma unroll 4
    for (int i = 0; i < 16; i++) {
        int r = rg * 16 + i;
        uint4 u = *(const uint4*)(&As[r * DD + ((cx ^ (r & 7)) * 8)]);
        float e = ew[r];
        nacc[0] += e * __builtin_bit_cast(float, u.x << 16);
        nacc[1] += e * __builtin_bit_cast(float, u.x & 0xFFFF0000u);
        nacc[2] += e * __builtin_bit_cast(float, u.y << 16);
        nacc[3] += e * __builtin_bit_cast(float, u.y & 0xFFFF0000u);
        nacc[4] += e * __builtin_bit_cast(float, u.z << 16);
        nacc[5] += e * __builtin_bit_cast(float, u.z & 0xFFFF0000u);
        nacc[6] += e * __builtin_bit_cast(float, u.w << 16);
        nacc[7] += e * __builtin_bit_cast(float, u.w & 0xFFFF0000u);
    }
    *(float4*)(&psum[rg][cx * 8])     = *(float4*)(&nacc[0]);
    *(float4*)(&psum[rg][cx * 8 + 4]) = *(float4*)(&nacc[4]);
    __syncthreads();

    if (tid < 128) {
        int c = tid * 4;
        f32x4 f = *(const f32x4*)(&psum[0][c]);
        f += *(const f32x4*)(&psum[1][c]);
        f += *(const f32x4*)(&psum[2][c]);
        f += *(const f32x4*)(&psum[3][c]);
        *(f32x4*)(num_ws + (size_t)blockIdx.x * DD + c) = f;
    }
    if (tid == 0) {
        mz_ws[2 * blockIdx.x]     = mzsh[0];
        mz_ws[2 * blockIdx.x + 1] = mzsh[1];
    }
}

// ---------------- Combine: merge 64 chunk-partials per batch -> out[b][512] ----------------
__global__ void combine_kernel(const float* __restrict__ num_ws,
                               const float* __restrict__ mz_ws,
                               float* __restrict__ out) {
    __shared__ float fs[64];
    __shared__ float sinv_sh;
    const int b   = blockIdx.x;
    const int tid = threadIdx.x;

    if (tid < 64) {
        float m = mz_ws[(b * 64 + tid) * 2];
        float z = mz_ws[(b * 64 + tid) * 2 + 1];
        float M = m;
        #pragma unroll
        for (int off = 32; off; off >>= 1) M = fmaxf(M, __shfl_xor(M, off));
        float f  = __expf(m - M);
        float fz = f * z;
        #pragma unroll
        for (int off = 32; off; off >>= 1) fz += __shfl_xor(fz, off);
        fs[tid] = f;
        if (tid == 0) sinv_sh = 1.0f / fz;
    }
    __syncthreads();

    float a0 = 0.f, a1 = 0.f;
    #pragma unroll 4
    for (int c = 0; c < 64; c++) {
        float f = fs[c];
        const float* np = num_ws + (size_t)(b * 64 + c) * DD;
        a0 += f * np[tid];
        a1 += f * np[tid + 256];
    }
    const float sinv = sinv_sh;
    out[b * DD + tid]       = a0 * sinv;
    out[b * DD + tid + 256] = a1 * sinv;
}

extern "C" void kernel_launch(void* const* d_in, const int* in_sizes, int n_in,
                              void* d_out, int out_size, void* d_ws, size_t ws_size,
                              hipStream_t stream) {
    (void)in_sizes; (void)n_in; (void)out_size; (void)ws_size;
    const float* x = (const float*)d_in[0];
    const float* W = (const float*)d_in[1];
    const float* v = (const float*)d_in[2];
    float* out = (float*)d_out;

    // ws: Wb 512 KB + 8 KB stream-overrun pad | num 1024x512 fp32 (2 MB) | mz 1024x2 fp32
    unsigned short* Wb = (unsigned short*)d_ws;
    float* num_ws      = (float*)((char*)d_ws + 512 * 1024 + 8 * 1024);
    float* mz_ws       = (float*)((char*)d_ws + 512 * 1024 + 8 * 1024 + 2 * 1024 * 1024);

    wb_kernel<<<128, 256, 0, stream>>>(W, Wb);

    scorepool_kernel<<<MM / 64, 256, 0, stream>>>(x, Wb, v, num_ws, mz_ws);

    combine_kernel<<<BB, 256, 0, stream>>>(num_ws, mz_ws, out);
}